// Round 1
// baseline (2648.597 us; speedup 1.0000x reference)
//
#include <hip/hip_runtime.h>

using u16 = unsigned short;
using u32 = unsigned int;
using ll  = long long;

typedef __attribute__((ext_vector_type(8)))  short bf8_t;   // 8 bf16 (4 VGPRs)
typedef __attribute__((ext_vector_type(4)))  float f32x4;
typedef __attribute__((ext_vector_type(16))) float f32x16;

#define DEVI __device__ __forceinline__

DEVI float b2f(u16 u){ union{u32 i; float f;} x; x.i=((u32)u)<<16; return x.f; }
DEVI u16 f2b(float f){ union{float f; u32 i;} x; x.f=f; u32 r=(x.i + 0x7fffu + ((x.i>>16)&1u))>>16; return (u16)r; }
DEVI f32x16 zero16(){ f32x16 v; for(int i=0;i<16;i++) v[i]=0.f; return v; }
// dtype-flexible input load: f==1 -> float32 buffer, f==0 -> bf16 buffer
DEVI float ldin(const void* p, ll i, int f){
  return f ? ((const float*)p)[i] : b2f(((const u16*)p)[i]);
}

DEVI bf8_t lds_frag(const u16* p){
  union{ u32 u[4]; bf8_t v; } t;
  const u32* q = (const u32*)p;
  t.u[0]=q[0]; t.u[1]=q[1]; t.u[2]=q[2]; t.u[3]=q[3];
  return t.v;
}
DEVI bf8_t g_frag(const u16* p){ return *(const bf8_t*)p; }

// ---------------- dtype probe: f32 mantissa junk has huge-exponent bf16 patterns ----------------
__global__ void k_probe(const u16* __restrict__ w, int* __restrict__ flag){
  __shared__ int cnt;
  if (threadIdx.x==0) cnt = 0;
  __syncthreads();
  int c = 0;
  for (int i = threadIdx.x; i < 65536; i += 256){
    u32 e = ((u32)w[i] >> 7) & 0xFF;
    if (e >= 0xC0) c++;
  }
  atomicAdd(&cnt, c);
  __syncthreads();
  if (threadIdx.x==0) *flag = (cnt > 64) ? 1 : 0;
}

// ---------------- conv weights -> 32x32x16 A-frag order ----------------
// kcMajor=0: [mt][kc][64lane*8]  (conv1, conv3)
// kcMajor=1: [kc][mt][64lane*8]  (conv2 -> enables contiguous per-kc LDS staging)
__global__ void k_wprep(const void* __restrict__ w, u16* __restrict__ dst, int C, int CH, int MT,
                        const int* __restrict__ flagp, int kcMajor){
  int tid = blockIdx.x*256 + threadIdx.x;
  int total = MT*CH*64;
  if (tid >= total) return;
  int f = *flagp;
  int l = tid & 63;
  int rest = tid >> 6;
  int kc = rest % CH;
  int mt = rest / CH;
  int o  = mt*32 + (l & 31);
  int c  = kc >> 3;
  int tap0 = (kc & 7)*16 + ((l>>5)&1)*8;
  union{ u16 v[8]; bf8_t vv; } t;
  for (int j=0;j<8;j++){
    int tap = tap0 + j;
    t.v[j] = (tap < 125) ? f2b(ldin(w, (ll)(o*C + c)*125 + tap, f)) : (u16)0;
  }
  size_t didx = kcMajor ? ((size_t)(kc*MT + mt)*64 + l) : (size_t)tid;
  *(bf8_t*)(dst + didx*8) = t.vv;
}

// ---------------- graph norm ----------------
__global__ void k_deg(const void* __restrict__ A, float* __restrict__ dinv,
                      const int* __restrict__ flagp){
  int c = blockIdx.x; int l = threadIdx.x; int f = *flagp;
  float s = 0.f;
  for (int r = l; r < 565; r += 64) s += ldin(A, (ll)c*565 + r, f);
  for (int off=32; off; off>>=1) s += __shfl_down(s, off, 64);
  if (l==0) dinv[c] = 1.0f / sqrtf(s + 1.0f);
}

__global__ void k_norm(const void* __restrict__ A, const float* __restrict__ dinv,
                       u16* __restrict__ normTp, const int* __restrict__ flagp){
  int i = blockIdx.x*256 + threadIdx.x;
  if (i >= 565*576) return;
  int f = *flagp;
  int c = i / 576, r = i - c*576;
  float v = 0.f;
  if (r < 565){
    float a = ldin(A, (ll)r*565 + c, f);
    if (r == c) a += 1.0f;
    v = dinv[c]*dinv[r]*a;
  }
  normTp[c*576 + r] = f2b(v);
}

// ---------------- generic B -> 16x16x32 frag swizzle ----------------
__global__ void k_bswz(const void* __restrict__ src, u16* __restrict__ dst,
                       int srcLd, int Kv, int Nv, int kcC, int ntC, int batch,
                       ll srcBS, ll dstBS, const int* __restrict__ flagp, int useF){
  int tid = blockIdx.x*256 + threadIdx.x;
  int total = batch*ntC*kcC*64;
  if (tid >= total) return;
  int f = useF ? *flagp : 0;
  int l = tid & 63;
  int rest = tid >> 6;
  int kc = rest % kcC; rest /= kcC;
  int nt = rest % ntC; int bi = rest/ntC;
  int n  = nt*16 + (l&15);
  int k0 = kc*32 + ((l>>4)&3)*8;
  union{ u16 v[8]; bf8_t vv; } t;
  for (int j=0;j<8;j++){
    int k = k0 + j;
    t.v[j] = (k < Kv && n < Nv) ? f2b(ldin(src, (ll)bi*srcBS + (ll)k*srcLd + n, f)) : (u16)0;
  }
  *(bf8_t*)(dst + (size_t)bi*dstBS + ((size_t)(nt*kcC + kc)*64 + l)*8) = t.vv;
}

__global__ void k_mvp(const void* __restrict__ mv, u16* __restrict__ mvp,
                      const int* __restrict__ flagp){
  int i = blockIdx.x*256 + threadIdx.x; if (i >= 16*576) return;
  int f = *flagp;
  int b = i/576, k = i - b*576;
  mvp[i] = (k < 565) ? f2b(ldin(mv, (ll)b*565 + k, f)) : (u16)0;
}

// ---------------- fused conv1+conv2 ----------------
// stage one 8-kc chunk (16KB) of kc-major w2 into LDS double buffer via async DMA
DEVI void stage_w2(const u16* __restrict__ w2p, u16* lds, int buf, int chunk, int tid){
  const u16* src = w2p + (size_t)chunk*8192;      // 8 kc * 1024 u16
  u16* dst = lds + 17104 + buf*8192;
  int w = tid>>6, l = tid&63;
  #pragma unroll
  for (int r=0;r<4;r++){
    int off = r*2048 + w*512;                     // u16 units; HW adds lane*16B at dest
    __builtin_amdgcn_global_load_lds(
      (const __attribute__((address_space(1))) void*)(src + off + l*8),
      (__attribute__((address_space(3))) void*)(dst + off),
      16, 0, 0);
  }
}

__launch_bounds__(256, 2)
__global__ void k_conv12(const void* __restrict__ wav, const u16* __restrict__ w1p,
                         const u16* __restrict__ w2p, const void* __restrict__ b1,
                         const void* __restrict__ b2, u16* __restrict__ y2c, int rowBase,
                         const int* __restrict__ flagp){
  // LDS map (u16): [0,3024) wavT[3][1004] | [3024,17104) y1T[32][440] | [17104,33488) w2 dbuf 2x8192
  __shared__ uint4 ldsr[4186];            // 66,976 B -> 2 blocks/CU
  u16* lds = (u16*)ldsr;
  const int Y1B = 3024;
  int tid = threadIdx.x; int row = rowBase + blockIdx.x;
  int f = *flagp;
  int l = tid&63, w = tid>>6;
  int lq = (l>>5)&1, col = l&31;
  for (int i = tid; i < 3012; i += 256){
    int c = i/1004; int t = i - c*1004;
    lds[i] = (t < 1000) ? f2b(ldin(wav, (ll)row*3000 + t*3 + c, f)) : (u16)0;
  }
  __syncthreads();
  // conv1 (unchanged: VMEM a-frags, w1p is tiny and L1-resident)
  f32x16 acc[4];
  #pragma unroll
  for(int t=0;t<4;t++) acc[t] = zero16();
  int pm1[4], pr1[4];
  #pragma unroll
  for(int t=0;t<4;t++){ int p = (w + 4*t)*32 + col; pm1[t]=p; pr1[t] = p>437?437:p; }
  for(int kc=0;kc<24;kc++){
    bf8_t a = g_frag(w1p + (size_t)kc*512 + (size_t)l*8);
    int ab = (kc>>3)*1004 + ((kc&7)*16 + lq*8);
    #pragma unroll
    for(int t=0;t<4;t++){
      bf8_t bf = lds_frag(lds + ab + 2*pr1[t]);
      acc[t] = __builtin_amdgcn_mfma_f32_32x32x16_bf16(a, bf, acc[t], 0,0,0);
    }
  }
  float bv1[16];
  #pragma unroll
  for(int r=0;r<16;r++){ int om = (r&3) + 8*(r>>2) + 4*lq; bv1[r] = ldin(b1, om, f); }
  #pragma unroll
  for(int t=0;t<4;t++){
    if (pm1[t] < 438){
      #pragma unroll
      for(int r=0;r<16;r++){
        int om = (r&3) + 8*(r>>2) + 4*lq;
        float v = acc[t][r] + bv1[r]; v = v>0.f?v:0.f;
        lds[Y1B + om*440 + pm1[t]] = f2b(v);
      }
    }
  }
  if (tid < 64) lds[Y1B + (tid>>1)*440 + 438 + (tid&1)] = 0;
  // prefetch chunk 0 of w2 while conv1 epilogue drains
  stage_w2(w2p, lds, 0, 0, tid);
  __syncthreads();

  // conv2: rebalanced {3,3,2,2} tile assignment + LDS-staged weights.
  // waves 0-3 own pos-tiles 0-3 (both och groups); tile 4's och0 -> wave0, och1 -> wave1.
  u16* y2row = y2c + (size_t)blockIdx.x*10240;
  f32x16 acP0 = zero16(), acP1 = zero16(), acX = zero16();
  int hasX = (w < 2) ? 1 : 0;
  int pP = w*32 + col;  int prP = pP>156?156:pP;
  int pX = 128 + col;   int prX = pX>156?156:pX;
  for (int ch=0; ch<32; ++ch){
    if (ch < 31) stage_w2(w2p, lds, (ch+1)&1, ch+1, tid);
    const u16* wb = lds + 17104 + (ch&1)*8192;
    int abb = Y1B + ch*440 + lq*8;
    #pragma unroll
    for (int kk=0; kk<8; ++kk){
      bf8_t a0 = lds_frag(wb + kk*1024 + l*8);
      bf8_t a1 = lds_frag(wb + kk*1024 + 512 + l*8);
      const u16* bp = lds + abb + kk*16;
      bf8_t bP = lds_frag(bp + 2*prP);
      acP0 = __builtin_amdgcn_mfma_f32_32x32x16_bf16(a0, bP, acP0, 0,0,0);
      acP1 = __builtin_amdgcn_mfma_f32_32x32x16_bf16(a1, bP, acP1, 0,0,0);
      if (hasX){
        bf8_t bX = lds_frag(bp + 2*prX);
        acX = __builtin_amdgcn_mfma_f32_32x32x16_bf16(w==0 ? a0 : a1, bX, acX, 0,0,0);
      }
    }
    __syncthreads();   // drains vmcnt (staging) + lgkmcnt; next chunk ready
  }
  if (pP < 157){
    #pragma unroll
    for(int r=0;r<16;r++){
      int om = (r&3) + 8*(r>>2) + 4*lq;
      float v0 = acP0[r] + ldin(b2, om, f);    v0 = v0>0.f?v0:0.f;
      float v1 = acP1[r] + ldin(b2, 32+om, f); v1 = v1>0.f?v1:0.f;
      y2row[om*160 + pP]      = f2b(v0);
      y2row[(32+om)*160 + pP] = f2b(v1);
    }
  }
  if (hasX && pX < 157){
    #pragma unroll
    for(int r=0;r<16;r++){
      int om = (r&3) + 8*(r>>2) + 4*lq;
      float v = acX[r] + ldin(b2, w*32 + om, f); v = v>0.f?v:0.f;
      y2row[(w*32+om)*160 + pX] = f2b(v);
    }
  }
  if (tid < 192){ int o = tid/3; y2row[o*160 + 157 + (tid - o*3)] = 0; }
}

// ---------------- conv3 (3 rows/WG), scatter into per-batch scrambled-reshape layout ----------------
__launch_bounds__(256, 2)
__global__ void k_conv3(const u16* __restrict__ y2c, int rowBase, int R, int batchBase,
                        const u16* __restrict__ w3p, const void* __restrict__ b3,
                        u16* __restrict__ y3c, const int* __restrict__ flagp){
  __shared__ uint4 lds4[3840];
  u16* lds = (u16*)lds4;
  int tid = threadIdx.x, wg = blockIdx.x;
  int f = *flagp;
  {
    const uint4* src = (const uint4*)y2c;
    ll lim = (ll)R*1280;
    ll base4 = (ll)wg*3840;
    for (int i = tid; i < 3840; i += 256){
      ll gi = base4 + i;
      uint4 v;
      if (gi < lim) v = src[gi]; else { v.x=0;v.y=0;v.z=0;v.w=0; }
      lds4[i] = v;
    }
  }
  __syncthreads();
  int l = tid&63, w = tid>>6;
  int lq = (l>>5)&1, col = l&31;
  int mtb = (w>>1)<<1;
  int nt  = w&1;
  int pf  = nt*32 + col;
  int pc  = pf>50?50:pf;
  int g   = pc/17; int wp = pc - g*17;
  int bbase = g*10240 + 2*wp;
  f32x16 ac0 = zero16(), ac1 = zero16();
  const u16* w3a = w3p + (size_t)mtb*262144;
  for(int kc=0;kc<512;kc++){
    bf8_t a0 = g_frag(w3a + (size_t)kc*512 + (size_t)l*8);
    bf8_t a1 = g_frag(w3a + 262144 + (size_t)kc*512 + (size_t)l*8);
    int ab = (kc>>3)*160 + ((kc&7)*16 + lq*8);
    bf8_t bf = lds_frag(lds + bbase + ab);
    ac0 = __builtin_amdgcn_mfma_f32_32x32x16_bf16(a0, bf, ac0, 0,0,0);
    ac1 = __builtin_amdgcn_mfma_f32_32x32x16_bf16(a1, bf, ac1, 0,0,0);
  }
  if (pf < 51 && (wg*3 + g) < R){
    int rowIdx = rowBase + wg*3 + g;
    int b = rowIdx/565; int n = rowIdx - b*565;
    int bb = b - batchBase;
    size_t obase = (size_t)bb*1229440 + (size_t)n*17 + wp;
    #pragma unroll
    for(int r=0;r<16;r++){
      int om = (r&3) + 8*(r>>2) + 4*lq;
      int o0 = mtb*32 + om, o1 = (mtb+1)*32 + om;
      float v0 = ac0[r] + ldin(b3, o0, f); v0 = v0>0.f?v0:0.f;
      float v1 = ac1[r] + ldin(b3, o1, f); v1 = v1>0.f?v1:0.f;
      y3c[obase + (size_t)o0*9605] = f2b(v0);
      y3c[obase + (size_t)o1*9605] = f2b(v1);
    }
  }
}

// ---------------- generic M=565-per-batch GEMM (16x16x32), N=64 ----------------
__global__ void k_gemm565(const u16* __restrict__ A, ll Abs, int lda,
                          const u16* __restrict__ bsw, ll Bbs, int KC,
                          const void* __restrict__ bias, int epi,
                          u16* __restrict__ outp, ll Obs, const int* __restrict__ flagp){
  int wg = blockIdx.x; int bi = wg/9; int mtg = wg - bi*9;
  int tid = threadIdx.x; int l = tid&63; int w = tid>>6;
  int f = *flagp;
  int Mt = mtg*4 + w;
  int m = Mt*16 + (l&15); int mc = m>564?564:m;
  int q = (l>>4)&3;
  const u16* Ab = A + (size_t)bi*Abs + (size_t)mc*lda + q*8;
  const u16* Bb = bsw + (size_t)bi*Bbs + (size_t)l*8;
  f32x4 ac[4];
  #pragma unroll
  for(int t=0;t<4;t++){ ac[t][0]=0;ac[t][1]=0;ac[t][2]=0;ac[t][3]=0; }
  for(int kc=0;kc<KC;kc++){
    bf8_t a = g_frag(Ab + kc*32);
    #pragma unroll
    for(int nt=0;nt<4;nt++){
      bf8_t bf = g_frag(Bb + (size_t)(nt*KC + kc)*512);
      ac[nt] = __builtin_amdgcn_mfma_f32_16x16x32_bf16(a, bf, ac[nt], 0,0,0);
    }
  }
  int rowb = q*4;
  #pragma unroll
  for(int nt=0;nt<4;nt++){
    int n = nt*16 + (l&15);
    float bv = bias ? ldin(bias, n, f) : 0.f;
    #pragma unroll
    for(int r=0;r<4;r++){
      int mm = Mt*16 + rowb + r;
      if (mm < 565){
        float v = ac[nt][r] + bv;
        if (epi==1) v = v>0.f?v:0.f;
        else if (epi==2) v = tanhf(v);
        outp[(size_t)bi*Obs + (size_t)mm*64 + n] = f2b(v);
      }
    }
  }
}

// ---------------- fc1: (16 x 36160) @ (36160 x 1280), K-split atomics ----------------
__global__ void k_fc1(const u16* __restrict__ z2, const void* __restrict__ wfc1,
                      float* __restrict__ acc, const int* __restrict__ flagp){
  int ng = blockIdx.x;     // 0..19
  int ks = blockIdx.y;     // 0..S-1
  int S  = gridDim.y;
  int tid = threadIdx.x; int l = tid&63; int w = tid>>6;
  int f = *flagp;
  int lo = (ks*1130)/S, hi = ((ks+1)*1130)/S;
  int colb = ng*64;
  int q = (l>>4)&3;
  f32x4 ac[4];
  #pragma unroll
  for(int t=0;t<4;t++){ ac[t][0]=0;ac[t][1]=0;ac[t][2]=0;ac[t][3]=0; }
  const u16* Ab = z2 + (size_t)(l&15)*36160 + q*8;
  for (int kc = lo + w; kc < hi; kc += 4){
    bf8_t a = g_frag(Ab + kc*32);
    int kb = kc*32 + q*8;
    #pragma unroll
    for (int nt=0;nt<4;nt++){
      int n = colb + nt*16 + (l&15);
      union{ u16 v[8]; bf8_t vv; } t;
      #pragma unroll
      for (int j=0;j<8;j++) t.v[j] = f2b(ldin(wfc1, (ll)(kb+j)*1280 + n, f));
      ac[nt] = __builtin_amdgcn_mfma_f32_16x16x32_bf16(a, t.vv, ac[nt], 0,0,0);
    }
  }
  int rowb = q*4;
  #pragma unroll
  for (int nt=0;nt<4;nt++){
    int n = colb + nt*16 + (l&15);
    #pragma unroll
    for (int r=0;r<4;r++) atomicAdd(&acc[(rowb+r)*1280 + n], ac[nt][r]);
  }
}

// ---------------- assemble z ----------------
__global__ void k_asm(const float* __restrict__ acc, const void* __restrict__ bfc1,
                      const void* __restrict__ meta, u16* __restrict__ z,
                      const int* __restrict__ flagp){
  int i = blockIdx.x*256 + threadIdx.x; if (i >= 16*1856) return;
  int f = *flagp;
  int b = i/1856, j = i - b*1856;
  if (j < 1280){ float v = acc[b*1280+j] + ldin(bfc1, j, f); z[i] = f2b(v>0.f?v:0.f); }
  else if (j < 1285) z[i] = f2b(ldin(meta, (ll)b*5 + (j-1280), f));
  else if (j >= 1850) z[i] = 0;
}

// ---------------- fc_extra into z cols [1285,1850), direct weight gather ----------------
__global__ void k_fce(const u16* __restrict__ mvp, const void* __restrict__ wfce,
                      const void* __restrict__ bias, u16* __restrict__ z,
                      const int* __restrict__ flagp){
  int nt = blockIdx.x; int l = threadIdx.x;
  int f = *flagp;
  int q = (l>>4)&3;
  f32x4 ac; ac[0]=0;ac[1]=0;ac[2]=0;ac[3]=0;
  const u16* Ab = mvp + (size_t)(l&15)*576 + q*8;
  int n = nt*16 + (l&15);
  for (int kc=0;kc<18;kc++){
    bf8_t a = g_frag(Ab + kc*32);
    union{ u16 v[8]; bf8_t vv; } t;
    #pragma unroll
    for (int j=0;j<8;j++){
      int k = kc*32 + q*8 + j;
      t.v[j] = (k < 565 && n < 565) ? f2b(ldin(wfce, (ll)k*565 + n, f)) : (u16)0;
    }
    ac = __builtin_amdgcn_mfma_f32_16x16x32_bf16(a, t.vv, ac, 0,0,0);
  }
  int rowb = q*4;
  if (n < 565){
    float bv = ldin(bias, n, f);
    #pragma unroll
    for (int r=0;r<4;r++){
      float v = ac[r] + bv; v = v>0.f?v:0.f;
      z[(size_t)(rowb+r)*1856 + 1285 + n] = f2b(v);
    }
  }
}

// ---------------- 5 output heads, direct weight gather, dtype-flexible store ----------------
__global__ void k_heads(const u16* __restrict__ z,
                        const void* __restrict__ wh0, const void* __restrict__ wh1,
                        const void* __restrict__ wh2, const void* __restrict__ wh3,
                        const void* __restrict__ wh4,
                        const void* __restrict__ bh0, const void* __restrict__ bh1,
                        const void* __restrict__ bh2, const void* __restrict__ bh3,
                        const void* __restrict__ bh4, void* __restrict__ out,
                        const int* __restrict__ flagp){
  int wg = blockIdx.x; int h = wg/36, nt = wg - h*36;
  int l = threadIdx.x;
  int f = *flagp;
  const void* wh   = (h==0)?wh0:(h==1)?wh1:(h==2)?wh2:(h==3)?wh3:wh4;
  const void* bias = (h==0)?bh0:(h==1)?bh1:(h==2)?bh2:(h==3)?bh3:bh4;
  int q = (l>>4)&3;
  f32x4 ac; ac[0]=0;ac[1]=0;ac[2]=0;ac[3]=0;
  const u16* Ab = z + (size_t)(l&15)*1856 + q*8;
  int n = nt*16 + (l&15);
  for (int kc=0;kc<58;kc++){
    bf8_t a = g_frag(Ab + kc*32);
    union{ u16 v[8]; bf8_t vv; } t;
    #pragma unroll
    for (int j=0;j<8;j++){
      int k = kc*32 + q*8 + j;
      t.v[j] = (k < 1850 && n < 565) ? f2b(ldin(wh, (ll)k*565 + n, f)) : (u16)0;
    }
    ac = __builtin_amdgcn_mfma_f32_16x16x32_bf16(a, t.vv, ac, 0,0,0);
  }
  int rowb = q*4;
  if (n < 565){
    float bv = ldin(bias, n, f);
    #pragma unroll
    for (int r=0;r<4;r++){
      float v = ac[r] + bv;
      size_t idx = (size_t)h*9040 + (size_t)(rowb+r)*565 + n;
      if (f) ((float*)out)[idx] = v; else ((u16*)out)[idx] = f2b(v);
    }
  }
}

extern "C" void kernel_launch(void* const* d_in, const int* in_sizes, int n_in,
                              void* d_out, int out_size, void* d_ws, size_t ws_size,
                              hipStream_t stream) {
  (void)in_sizes; (void)n_in; (void)out_size;
  const void* wav   = d_in[0];
  const void* graph = d_in[2];
  const void* meta  = d_in[3];
  const void* mv    = d_in[4];
  const void* w_c1  = d_in[5];  const void* b_c1 = d_in[6];
  const void* w_c2  = d_in[7];  const void* b_c2 = d_in[8];
  const void* w_c3  = d_in[9];  const void* b_c3 = d_in[10];
  const void* w_g1  = d_in[11]; const void* b_g1 = d_in[12];
  const void* w_g2  = d_in[13]; const void* b_g2 = d_in[14];
  const void* w_fce = d_in[15]; const void* b_fce= d_in[16];
  const void* w_fc1 = d_in[17]; const void* b_fc1= d_in[18];
  const void* w_h0 = d_in[19]; const void* b_h0 = d_in[20];
  const void* w_h1 = d_in[21]; const void* b_h1 = d_in[22];
  const void* w_h2 = d_in[23]; const void* b_h2 = d_in[24];
  const void* w_h3 = d_in[25]; const void* b_h3 = d_in[26];
  const void* w_h4 = d_in[27]; const void* b_h4 = d_in[28];

  char* wsb = (char*)d_ws;
  size_t off = 0;
  auto carve = [&](size_t bytes)->char*{ char* p = wsb + off; off = (off + bytes + 255) & ~(size_t)255; return p; };
  int*  flagp = (int*) carve(4);
  u16*  w1p   = (u16*) carve(12288ull*2);
  u16*  w2p   = (u16*) carve(262144ull*2);
  u16*  w3p   = (u16*) carve(1048576ull*2);
  float* dinv = (float*)carve(576*4);
  u16*  normTp= (u16*) carve(576ull*576*2);
  u16*  bswg1 = (u16*) carve(139264ull*2);
  u16*  bswg2 = (u16*) carve(4096ull*2);
  u16*  hbuf  = (u16*) carve(578560ull*2);
  u16*  bswh  = (u16*) carve(589824ull*2);
  u16*  z1    = (u16*) carve(578560ull*2);
  u16*  h2    = (u16*) carve(578560ull*2);
  u16*  bswh2 = (u16*) carve(589824ull*2);
  u16*  z2    = (u16*) carve(578560ull*2);
  float* facc = (float*)carve(20480*4);
  u16*  zbuf  = (u16*) carve(16ull*1856*2);
  u16*  mvp   = (u16*) carve(9216ull*2);
  // batch-chunked conv intermediates sized from the REAL ws_size
  size_t fixed = off;
  ll per_b = 565LL*10240*2 + 1229440LL*2;           // y2 + y3 per batch = 14,030,080 B
  ll avail = (ll)ws_size - (ll)fixed - 4096;
  int BPC = (int)(avail / per_b);
  if (BPC < 1) BPC = 1; if (BPC > 16) BPC = 16;
  u16* y2c = (u16*)(wsb + fixed);
  u16* y3c = y2c + (size_t)BPC*565*10240;

  hipMemsetAsync(facc, 0, 20480*4, stream);
  k_probe<<<1,256,0,stream>>>((const u16*)w_fc1, flagp);
  // weight preps
  k_wprep<<<6,  256,0,stream>>>(w_c1, w1p, 3,  24,  1, flagp, 0);
  k_wprep<<<128,256,0,stream>>>(w_c2, w2p, 32, 256, 2, flagp, 1);   // kc-major for LDS staging
  k_wprep<<<512,256,0,stream>>>(w_c3, w3p, 64, 512, 4, flagp, 0);
  k_deg<<<565,64,0,stream>>>(graph, dinv, flagp);
  k_norm<<<1272,256,0,stream>>>(graph, dinv, normTp, flagp);
  k_bswz<<<68, 256,0,stream>>>(w_g1, bswg1, 64, 2176, 64, 68, 4, 1, 0, 0, flagp, 1);
  k_bswz<<<2,  256,0,stream>>>(w_g2, bswg2, 64, 64,   64, 2,  4, 1, 0, 0, flagp, 1);
  k_mvp<<<36,256,0,stream>>>(mv, mvp, flagp);
  // conv stack + GEMM1, chunked by batch (stream order makes reuse safe)
  for (int cb = 0; cb < 16; cb += BPC){
    int nb = 16 - cb; if (nb > BPC) nb = BPC;
    int rows = nb*565;
    k_conv12<<<rows,256,0,stream>>>(wav, w1p, w2p, b_c1, b_c2, y2c, cb*565, flagp);
    k_conv3<<<(rows+2)/3,256,0,stream>>>(y2c, cb*565, rows, cb, w3p, b_c3, y3c, flagp);
    k_gemm565<<<nb*9,256,0,stream>>>(y3c, 1229440LL, 2176, bswg1, 0LL, 68, nullptr, 0,
                                     hbuf + (size_t)cb*36160, 36160LL, flagp);
  }
  // GCN aggregations
  k_bswz<<<288,256,0,stream>>>(hbuf, bswh, 64, 565, 64, 18, 4, 16, 36160LL, 36864LL, flagp, 0);
  k_gemm565<<<144,256,0,stream>>>(normTp, 0LL, 576, bswh, 36864LL, 18, b_g1, 1, z1, 36160LL, flagp);
  k_gemm565<<<144,256,0,stream>>>(z1, 36160LL, 64, bswg2, 0LL, 2, nullptr, 0, h2, 36160LL, flagp);
  k_bswz<<<288,256,0,stream>>>(h2, bswh2, 64, 565, 64, 18, 4, 16, 36160LL, 36864LL, flagp, 0);
  k_gemm565<<<144,256,0,stream>>>(normTp, 0LL, 576, bswh2, 36864LL, 18, b_g2, 2, z2, 36160LL, flagp);
  // head assembly
  k_fc1<<<dim3(20,48),256,0,stream>>>(z2, w_fc1, facc, flagp);
  k_asm<<<116,256,0,stream>>>(facc, b_fc1, meta, zbuf, flagp);
  k_fce<<<36,64,0,stream>>>(mvp, w_fce, b_fce, zbuf, flagp);
  k_heads<<<180,64,0,stream>>>(zbuf, w_h0, w_h1, w_h2, w_h3, w_h4,
                               b_h0, b_h1, b_h2, b_h3, b_h4, d_out, flagp);
}

// Round 2
// 2338.116 us; speedup vs baseline: 1.1328x; 1.1328x over previous
//
#include <hip/hip_runtime.h>

using u16 = unsigned short;
using u32 = unsigned int;
using ll  = long long;

typedef __attribute__((ext_vector_type(8)))  short bf8_t;   // 8 bf16 (4 VGPRs)
typedef __attribute__((ext_vector_type(4)))  float f32x4;
typedef __attribute__((ext_vector_type(16))) float f32x16;

#define DEVI __device__ __forceinline__

DEVI float b2f(u16 u){ union{u32 i; float f;} x; x.i=((u32)u)<<16; return x.f; }
DEVI u16 f2b(float f){ union{float f; u32 i;} x; x.f=f; u32 r=(x.i + 0x7fffu + ((x.i>>16)&1u))>>16; return (u16)r; }
DEVI f32x16 zero16(){ f32x16 v; for(int i=0;i<16;i++) v[i]=0.f; return v; }
// dtype-flexible input load: f==1 -> float32 buffer, f==0 -> bf16 buffer
DEVI float ldin(const void* p, ll i, int f){
  return f ? ((const float*)p)[i] : b2f(((const u16*)p)[i]);
}

DEVI bf8_t lds_frag(const u16* p){
  union{ u32 u[4]; bf8_t v; } t;
  const u32* q = (const u32*)p;
  t.u[0]=q[0]; t.u[1]=q[1]; t.u[2]=q[2]; t.u[3]=q[3];
  return t.v;
}
DEVI bf8_t g_frag(const u16* p){ return *(const bf8_t*)p; }

// ---------------- dtype probe: f32 mantissa junk has huge-exponent bf16 patterns ----------------
__global__ void k_probe(const u16* __restrict__ w, int* __restrict__ flag){
  __shared__ int cnt;
  if (threadIdx.x==0) cnt = 0;
  __syncthreads();
  int c = 0;
  for (int i = threadIdx.x; i < 65536; i += 256){
    u32 e = ((u32)w[i] >> 7) & 0xFF;
    if (e >= 0xC0) c++;
  }
  atomicAdd(&cnt, c);
  __syncthreads();
  if (threadIdx.x==0) *flag = (cnt > 64) ? 1 : 0;
}

// ---------------- conv weights -> 32x32x16 A-frag order ----------------
// kcMajor=0: [mt][kc][64lane*8]  (conv1, conv3)
// kcMajor=1: [kc][mt][64lane*8]  (conv2: a0/a1 adjacent per kc -> L1-friendly)
__global__ void k_wprep(const void* __restrict__ w, u16* __restrict__ dst, int C, int CH, int MT,
                        const int* __restrict__ flagp, int kcMajor){
  int tid = blockIdx.x*256 + threadIdx.x;
  int total = MT*CH*64;
  if (tid >= total) return;
  int f = *flagp;
  int l = tid & 63;
  int rest = tid >> 6;
  int kc = rest % CH;
  int mt = rest / CH;
  int o  = mt*32 + (l & 31);
  int c  = kc >> 3;
  int tap0 = (kc & 7)*16 + ((l>>5)&1)*8;
  union{ u16 v[8]; bf8_t vv; } t;
  for (int j=0;j<8;j++){
    int tap = tap0 + j;
    t.v[j] = (tap < 125) ? f2b(ldin(w, (ll)(o*C + c)*125 + tap, f)) : (u16)0;
  }
  size_t didx = kcMajor ? ((size_t)(kc*MT + mt)*64 + l) : (size_t)tid;
  *(bf8_t*)(dst + didx*8) = t.vv;
}

// ---------------- graph norm ----------------
__global__ void k_deg(const void* __restrict__ A, float* __restrict__ dinv,
                      const int* __restrict__ flagp){
  int c = blockIdx.x; int l = threadIdx.x; int f = *flagp;
  float s = 0.f;
  for (int r = l; r < 565; r += 64) s += ldin(A, (ll)c*565 + r, f);
  for (int off=32; off; off>>=1) s += __shfl_down(s, off, 64);
  if (l==0) dinv[c] = 1.0f / sqrtf(s + 1.0f);
}

__global__ void k_norm(const void* __restrict__ A, const float* __restrict__ dinv,
                       u16* __restrict__ normTp, const int* __restrict__ flagp){
  int i = blockIdx.x*256 + threadIdx.x;
  if (i >= 565*576) return;
  int f = *flagp;
  int c = i / 576, r = i - c*576;
  float v = 0.f;
  if (r < 565){
    float a = ldin(A, (ll)r*565 + c, f);
    if (r == c) a += 1.0f;
    v = dinv[c]*dinv[r]*a;
  }
  normTp[c*576 + r] = f2b(v);
}

// ---------------- generic B -> 16x16x32 frag swizzle ----------------
__global__ void k_bswz(const void* __restrict__ src, u16* __restrict__ dst,
                       int srcLd, int Kv, int Nv, int kcC, int ntC, int batch,
                       ll srcBS, ll dstBS, const int* __restrict__ flagp, int useF){
  int tid = blockIdx.x*256 + threadIdx.x;
  int total = batch*ntC*kcC*64;
  if (tid >= total) return;
  int f = useF ? *flagp : 0;
  int l = tid & 63;
  int rest = tid >> 6;
  int kc = rest % kcC; rest /= kcC;
  int nt = rest % ntC; int bi = rest/ntC;
  int n  = nt*16 + (l&15);
  int k0 = kc*32 + ((l>>4)&3)*8;
  union{ u16 v[8]; bf8_t vv; } t;
  for (int j=0;j<8;j++){
    int k = k0 + j;
    t.v[j] = (k < Kv && n < Nv) ? f2b(ldin(src, (ll)bi*srcBS + (ll)k*srcLd + n, f)) : (u16)0;
  }
  *(bf8_t*)(dst + (size_t)bi*dstBS + ((size_t)(nt*kcC + kc)*64 + l)*8) = t.vv;
}

__global__ void k_mvp(const void* __restrict__ mv, u16* __restrict__ mvp,
                      const int* __restrict__ flagp){
  int i = blockIdx.x*256 + threadIdx.x; if (i >= 16*576) return;
  int f = *flagp;
  int b = i/576, k = i - b*576;
  mvp[i] = (k < 565) ? f2b(ldin(mv, (ll)b*565 + k, f)) : (u16)0;
}

// ---------------- fused conv1+conv2 ----------------
// conv2 wave roles (balances VMEM / LDS / MFMA pipes at ~96cy each per block per kc):
//   wave0: och-grp0, pos-tiles {0,1,2}  (1 a-frag, 3 b-frags, 3 MFMA)
//   wave1: och-grp1, pos-tiles {0,1,2}  (1 a-frag, 3 b-frags, 3 MFMA)
//   wave2: both och, pos-tile 3         (2 a-frags, 1 b-frag, 2 MFMA)
//   wave3: both och, pos-tile 4         (2 a-frags, 1 b-frag, 2 MFMA)
__launch_bounds__(256, 2)
__global__ void k_conv12(const void* __restrict__ wav, const u16* __restrict__ w1p,
                         const u16* __restrict__ w2p, const void* __restrict__ b1,
                         const void* __restrict__ b2, u16* __restrict__ y2c, int rowBase,
                         const int* __restrict__ flagp){
  __shared__ uint4 ldsr[2138];            // 34,208 B = wavT[3][1004] + y1T[32][440]
  u16* lds = (u16*)ldsr;
  const int Y1B = 3024;
  int tid = threadIdx.x; int row = rowBase + blockIdx.x;
  int f = *flagp;
  int l = tid&63, w = tid>>6;
  int lq = (l>>5)&1, col = l&31;
  for (int i = tid; i < 3012; i += 256){
    int c = i/1004; int t = i - c*1004;
    lds[i] = (t < 1000) ? f2b(ldin(wav, (ll)row*3000 + t*3 + c, f)) : (u16)0;
  }
  __syncthreads();
  // conv1: tiles w+4t; tiles 14,15 (w>=2, t==3) cover pos >=448 > 437 -> dead, skip
  f32x16 acc[4];
  #pragma unroll
  for(int t=0;t<4;t++) acc[t] = zero16();
  int pm1[4], pr1[4];
  #pragma unroll
  for(int t=0;t<4;t++){ int p = (w + 4*t)*32 + col; pm1[t]=p; pr1[t] = p>437?437:p; }
  for(int kc=0;kc<24;kc++){
    bf8_t a = g_frag(w1p + (size_t)kc*512 + (size_t)l*8);
    int ab = (kc>>3)*1004 + ((kc&7)*16 + lq*8);
    #pragma unroll
    for(int t=0;t<4;t++){
      if (t==3 && w>=2) continue;     // wave-uniform dead-tile skip
      bf8_t bf = lds_frag(lds + ab + 2*pr1[t]);
      acc[t] = __builtin_amdgcn_mfma_f32_32x32x16_bf16(a, bf, acc[t], 0,0,0);
    }
  }
  float bv1[16];
  #pragma unroll
  for(int r=0;r<16;r++){ int om = (r&3) + 8*(r>>2) + 4*lq; bv1[r] = ldin(b1, om, f); }
  #pragma unroll
  for(int t=0;t<4;t++){
    if (pm1[t] < 438){
      #pragma unroll
      for(int r=0;r<16;r++){
        int om = (r&3) + 8*(r>>2) + 4*lq;
        float v = acc[t][r] + bv1[r]; v = v>0.f?v:0.f;
        lds[Y1B + om*440 + pm1[t]] = f2b(v);
      }
    }
  }
  if (tid < 64) lds[Y1B + (tid>>1)*440 + 438 + (tid&1)] = 0;
  __syncthreads();

  // conv2 hybrid
  u16* y2row = y2c + (size_t)blockIdx.x*10240;
  f32x16 ac2[3];
  ac2[0]=zero16(); ac2[1]=zero16(); ac2[2]=zero16();
  int isO = (w < 2);
  int pm2[3], pr2[3];
  if (isO){
    #pragma unroll
    for(int t=0;t<3;t++){ int p = t*32 + col; pm2[t]=p; pr2[t] = p>156?156:p; }
  } else {
    int p = (w+1)*32 + col; pm2[0]=p; pr2[0] = p>156?156:p;
    pm2[1]=0; pm2[2]=0; pr2[1]=0; pr2[2]=0;
  }
  for(int kc=0;kc<256;kc++){
    int ab = Y1B + (kc>>3)*440 + ((kc&7)*16 + lq*8);
    if (isO){
      bf8_t a = g_frag(w2p + (size_t)kc*1024 + (size_t)w*512 + (size_t)l*8);
      #pragma unroll
      for(int t=0;t<3;t++){
        bf8_t bf = lds_frag(lds + ab + 2*pr2[t]);
        ac2[t] = __builtin_amdgcn_mfma_f32_32x32x16_bf16(a, bf, ac2[t], 0,0,0);
      }
    } else {
      bf8_t a0 = g_frag(w2p + (size_t)kc*1024 + (size_t)l*8);
      bf8_t a1 = g_frag(w2p + (size_t)kc*1024 + 512 + (size_t)l*8);
      bf8_t bf = lds_frag(lds + ab + 2*pr2[0]);
      ac2[0] = __builtin_amdgcn_mfma_f32_32x32x16_bf16(a0, bf, ac2[0], 0,0,0);
      ac2[1] = __builtin_amdgcn_mfma_f32_32x32x16_bf16(a1, bf, ac2[1], 0,0,0);
    }
  }
  if (isO){
    int ochb = w*32;
    #pragma unroll
    for(int t=0;t<3;t++){
      if (pm2[t] < 157){
        #pragma unroll
        for(int r=0;r<16;r++){
          int om = (r&3) + 8*(r>>2) + 4*lq;
          float v = ac2[t][r] + ldin(b2, ochb+om, f); v = v>0.f?v:0.f;
          y2row[(ochb+om)*160 + pm2[t]] = f2b(v);
        }
      }
    }
  } else {
    if (pm2[0] < 157){
      #pragma unroll
      for(int r=0;r<16;r++){
        int om = (r&3) + 8*(r>>2) + 4*lq;
        float v0 = ac2[0][r] + ldin(b2, om, f);    v0 = v0>0.f?v0:0.f;
        float v1 = ac2[1][r] + ldin(b2, 32+om, f); v1 = v1>0.f?v1:0.f;
        y2row[om*160 + pm2[0]]      = f2b(v0);
        y2row[(32+om)*160 + pm2[0]] = f2b(v1);
      }
    }
  }
  if (tid < 192){ int o = tid/3; y2row[o*160 + 157 + (tid - o*3)] = 0; }
}

// ---------------- conv3 (3 rows/WG), och-major waves: 1 a-frag + 2 b-frags + 2 MFMA/kc ----------------
__launch_bounds__(256, 2)
__global__ void k_conv3(const u16* __restrict__ y2c, int rowBase, int R, int batchBase,
                        const u16* __restrict__ w3p, const void* __restrict__ b3,
                        u16* __restrict__ y3c, const int* __restrict__ flagp){
  __shared__ uint4 lds4[3840];
  u16* lds = (u16*)lds4;
  int tid = threadIdx.x, wg = blockIdx.x;
  int f = *flagp;
  {
    const uint4* src = (const uint4*)y2c;
    ll lim = (ll)R*1280;
    ll base4 = (ll)wg*3840;
    for (int i = tid; i < 3840; i += 256){
      ll gi = base4 + i;
      uint4 v;
      if (gi < lim) v = src[gi]; else { v.x=0;v.y=0;v.z=0;v.w=0; }
      lds4[i] = v;
    }
  }
  __syncthreads();
  int l = tid&63, w = tid>>6;
  int lq = (l>>5)&1, col = l&31;
  int mt = w;                          // och tile (32 och) owned by this wave
  int pf0 = col,      pf1 = 32 + col; // both position halves
  int pc0 = pf0>50?50:pf0, pc1 = pf1>50?50:pf1;
  int g0 = pc0/17, wp0 = pc0 - g0*17;
  int g1 = pc1/17, wp1 = pc1 - g1*17;
  int bb0 = g0*10240 + 2*wp0;
  int bb1 = g1*10240 + 2*wp1;
  f32x16 ac0 = zero16(), ac1 = zero16();
  const u16* w3a = w3p + (size_t)mt*262144;
  for(int kc=0;kc<512;kc++){
    bf8_t a = g_frag(w3a + (size_t)kc*512 + (size_t)l*8);
    int ab = (kc>>3)*160 + ((kc&7)*16 + lq*8);
    bf8_t bf0 = lds_frag(lds + bb0 + ab);
    bf8_t bf1 = lds_frag(lds + bb1 + ab);
    ac0 = __builtin_amdgcn_mfma_f32_32x32x16_bf16(a, bf0, ac0, 0,0,0);
    ac1 = __builtin_amdgcn_mfma_f32_32x32x16_bf16(a, bf1, ac1, 0,0,0);
  }
  #pragma unroll
  for (int h=0; h<2; ++h){
    int pf = h ? pf1 : pf0;
    int g  = h ? g1  : g0;
    int wp = h ? wp1 : wp0;
    if (pf < 51 && (wg*3 + g) < R){
      int rowIdx = rowBase + wg*3 + g;
      int b = rowIdx/565; int n = rowIdx - b*565;
      int bb = b - batchBase;
      size_t obase = (size_t)bb*1229440 + (size_t)n*17 + wp;
      #pragma unroll
      for(int r=0;r<16;r++){
        int om = (r&3) + 8*(r>>2) + 4*lq;
        int o = mt*32 + om;
        float v = (h ? ac1[r] : ac0[r]) + ldin(b3, o, f); v = v>0.f?v:0.f;
        y3c[obase + (size_t)o*9605] = f2b(v);
      }
    }
  }
}

// ---------------- generic M=565-per-batch GEMM (16x16x32), N=64 ----------------
__global__ void k_gemm565(const u16* __restrict__ A, ll Abs, int lda,
                          const u16* __restrict__ bsw, ll Bbs, int KC,
                          const void* __restrict__ bias, int epi,
                          u16* __restrict__ outp, ll Obs, const int* __restrict__ flagp){
  int wg = blockIdx.x; int bi = wg/9; int mtg = wg - bi*9;
  int tid = threadIdx.x; int l = tid&63; int w = tid>>6;
  int f = *flagp;
  int Mt = mtg*4 + w;
  int m = Mt*16 + (l&15); int mc = m>564?564:m;
  int q = (l>>4)&3;
  const u16* Ab = A + (size_t)bi*Abs + (size_t)mc*lda + q*8;
  const u16* Bb = bsw + (size_t)bi*Bbs + (size_t)l*8;
  f32x4 ac[4];
  #pragma unroll
  for(int t=0;t<4;t++){ ac[t][0]=0;ac[t][1]=0;ac[t][2]=0;ac[t][3]=0; }
  for(int kc=0;kc<KC;kc++){
    bf8_t a = g_frag(Ab + kc*32);
    #pragma unroll
    for(int nt=0;nt<4;nt++){
      bf8_t bf = g_frag(Bb + (size_t)(nt*KC + kc)*512);
      ac[nt] = __builtin_amdgcn_mfma_f32_16x16x32_bf16(a, bf, ac[nt], 0,0,0);
    }
  }
  int rowb = q*4;
  #pragma unroll
  for(int nt=0;nt<4;nt++){
    int n = nt*16 + (l&15);
    float bv = bias ? ldin(bias, n, f) : 0.f;
    #pragma unroll
    for(int r=0;r<4;r++){
      int mm = Mt*16 + rowb + r;
      if (mm < 565){
        float v = ac[nt][r] + bv;
        if (epi==1) v = v>0.f?v:0.f;
        else if (epi==2) v = tanhf(v);
        outp[(size_t)bi*Obs + (size_t)mm*64 + n] = f2b(v);
      }
    }
  }
}

// ---------------- fc1: (16 x 36160) @ (36160 x 1280), K-split atomics ----------------
__global__ void k_fc1(const u16* __restrict__ z2, const void* __restrict__ wfc1,
                      float* __restrict__ acc, const int* __restrict__ flagp){
  int ng = blockIdx.x;     // 0..19
  int ks = blockIdx.y;     // 0..S-1
  int S  = gridDim.y;
  int tid = threadIdx.x; int l = tid&63; int w = tid>>6;
  int f = *flagp;
  int lo = (ks*1130)/S, hi = ((ks+1)*1130)/S;
  int colb = ng*64;
  int q = (l>>4)&3;
  f32x4 ac[4];
  #pragma unroll
  for(int t=0;t<4;t++){ ac[t][0]=0;ac[t][1]=0;ac[t][2]=0;ac[t][3]=0; }
  const u16* Ab = z2 + (size_t)(l&15)*36160 + q*8;
  for (int kc = lo + w; kc < hi; kc += 4){
    bf8_t a = g_frag(Ab + kc*32);
    int kb = kc*32 + q*8;
    #pragma unroll
    for (int nt=0;nt<4;nt++){
      int n = colb + nt*16 + (l&15);
      union{ u16 v[8]; bf8_t vv; } t;
      #pragma unroll
      for (int j=0;j<8;j++) t.v[j] = f2b(ldin(wfc1, (ll)(kb+j)*1280 + n, f));
      ac[nt] = __builtin_amdgcn_mfma_f32_16x16x32_bf16(a, t.vv, ac[nt], 0,0,0);
    }
  }
  int rowb = q*4;
  #pragma unroll
  for (int nt=0;nt<4;nt++){
    int n = colb + nt*16 + (l&15);
    #pragma unroll
    for (int r=0;r<4;r++) atomicAdd(&acc[(rowb+r)*1280 + n], ac[nt][r]);
  }
}

// ---------------- assemble z ----------------
__global__ void k_asm(const float* __restrict__ acc, const void* __restrict__ bfc1,
                      const void* __restrict__ meta, u16* __restrict__ z,
                      const int* __restrict__ flagp){
  int i = blockIdx.x*256 + threadIdx.x; if (i >= 16*1856) return;
  int f = *flagp;
  int b = i/1856, j = i - b*1856;
  if (j < 1280){ float v = acc[b*1280+j] + ldin(bfc1, j, f); z[i] = f2b(v>0.f?v:0.f); }
  else if (j < 1285) z[i] = f2b(ldin(meta, (ll)b*5 + (j-1280), f));
  else if (j >= 1850) z[i] = 0;
}

// ---------------- fc_extra into z cols [1285,1850), direct weight gather ----------------
__global__ void k_fce(const u16* __restrict__ mvp, const void* __restrict__ wfce,
                      const void* __restrict__ bias, u16* __restrict__ z,
                      const int* __restrict__ flagp){
  int nt = blockIdx.x; int l = threadIdx.x;
  int f = *flagp;
  int q = (l>>4)&3;
  f32x4 ac; ac[0]=0;ac[1]=0;ac[2]=0;ac[3]=0;
  const u16* Ab = mvp + (size_t)(l&15)*576 + q*8;
  int n = nt*16 + (l&15);
  for (int kc=0;kc<18;kc++){
    bf8_t a = g_frag(Ab + kc*32);
    union{ u16 v[8]; bf8_t vv; } t;
    #pragma unroll
    for (int j=0;j<8;j++){
      int k = kc*32 + q*8 + j;
      t.v[j] = (k < 565 && n < 565) ? f2b(ldin(wfce, (ll)k*565 + n, f)) : (u16)0;
    }
    ac = __builtin_amdgcn_mfma_f32_16x16x32_bf16(a, t.vv, ac, 0,0,0);
  }
  int rowb = q*4;
  if (n < 565){
    float bv = ldin(bias, n, f);
    #pragma unroll
    for (int r=0;r<4;r++){
      float v = ac[r] + bv; v = v>0.f?v:0.f;
      z[(size_t)(rowb+r)*1856 + 1285 + n] = f2b(v);
    }
  }
}

// ---------------- 5 output heads, direct weight gather, dtype-flexible store ----------------
__global__ void k_heads(const u16* __restrict__ z,
                        const void* __restrict__ wh0, const void* __restrict__ wh1,
                        const void* __restrict__ wh2, const void* __restrict__ wh3,
                        const void* __restrict__ wh4,
                        const void* __restrict__ bh0, const void* __restrict__ bh1,
                        const void* __restrict__ bh2, const void* __restrict__ bh3,
                        const void* __restrict__ bh4, void* __restrict__ out,
                        const int* __restrict__ flagp){
  int wg = blockIdx.x; int h = wg/36, nt = wg - h*36;
  int l = threadIdx.x;
  int f = *flagp;
  const void* wh   = (h==0)?wh0:(h==1)?wh1:(h==2)?wh2:(h==3)?wh3:wh4;
  const void* bias = (h==0)?bh0:(h==1)?bh1:(h==2)?bh2:(h==3)?bh3:bh4;
  int q = (l>>4)&3;
  f32x4 ac; ac[0]=0;ac[1]=0;ac[2]=0;ac[3]=0;
  const u16* Ab = z + (size_t)(l&15)*1856 + q*8;
  int n = nt*16 + (l&15);
  for (int kc=0;kc<58;kc++){
    bf8_t a = g_frag(Ab + kc*32);
    union{ u16 v[8]; bf8_t vv; } t;
    #pragma unroll
    for (int j=0;j<8;j++){
      int k = kc*32 + q*8 + j;
      t.v[j] = (k < 1850 && n < 565) ? f2b(ldin(wh, (ll)k*565 + n, f)) : (u16)0;
    }
    ac = __builtin_amdgcn_mfma_f32_16x16x32_bf16(a, t.vv, ac, 0,0,0);
  }
  int rowb = q*4;
  if (n < 565){
    float bv = ldin(bias, n, f);
    #pragma unroll
    for (int r=0;r<4;r++){
      float v = ac[r] + bv;
      size_t idx = (size_t)h*9040 + (size_t)(rowb+r)*565 + n;
      if (f) ((float*)out)[idx] = v; else ((u16*)out)[idx] = f2b(v);
    }
  }
}

extern "C" void kernel_launch(void* const* d_in, const int* in_sizes, int n_in,
                              void* d_out, int out_size, void* d_ws, size_t ws_size,
                              hipStream_t stream) {
  (void)in_sizes; (void)n_in; (void)out_size;
  const void* wav   = d_in[0];
  const void* graph = d_in[2];
  const void* meta  = d_in[3];
  const void* mv    = d_in[4];
  const void* w_c1  = d_in[5];  const void* b_c1 = d_in[6];
  const void* w_c2  = d_in[7];  const void* b_c2 = d_in[8];
  const void* w_c3  = d_in[9];  const void* b_c3 = d_in[10];
  const void* w_g1  = d_in[11]; const void* b_g1 = d_in[12];
  const void* w_g2  = d_in[13]; const void* b_g2 = d_in[14];
  const void* w_fce = d_in[15]; const void* b_fce= d_in[16];
  const void* w_fc1 = d_in[17]; const void* b_fc1= d_in[18];
  const void* w_h0 = d_in[19]; const void* b_h0 = d_in[20];
  const void* w_h1 = d_in[21]; const void* b_h1 = d_in[22];
  const void* w_h2 = d_in[23]; const void* b_h2 = d_in[24];
  const void* w_h3 = d_in[25]; const void* b_h3 = d_in[26];
  const void* w_h4 = d_in[27]; const void* b_h4 = d_in[28];

  char* wsb = (char*)d_ws;
  size_t off = 0;
  auto carve = [&](size_t bytes)->char*{ char* p = wsb + off; off = (off + bytes + 255) & ~(size_t)255; return p; };
  int*  flagp = (int*) carve(4);
  u16*  w1p   = (u16*) carve(12288ull*2);
  u16*  w2p   = (u16*) carve(262144ull*2);
  u16*  w3p   = (u16*) carve(1048576ull*2);
  float* dinv = (float*)carve(576*4);
  u16*  normTp= (u16*) carve(576ull*576*2);
  u16*  bswg1 = (u16*) carve(139264ull*2);
  u16*  bswg2 = (u16*) carve(4096ull*2);
  u16*  hbuf  = (u16*) carve(578560ull*2);
  u16*  bswh  = (u16*) carve(589824ull*2);
  u16*  z1    = (u16*) carve(578560ull*2);
  u16*  h2    = (u16*) carve(578560ull*2);
  u16*  bswh2 = (u16*) carve(589824ull*2);
  u16*  z2    = (u16*) carve(578560ull*2);
  float* facc = (float*)carve(20480*4);
  u16*  zbuf  = (u16*) carve(16ull*1856*2);
  u16*  mvp   = (u16*) carve(9216ull*2);
  // batch-chunked conv intermediates sized from the REAL ws_size
  size_t fixed = off;
  ll per_b = 565LL*10240*2 + 1229440LL*2;           // y2 + y3 per batch = 14,030,080 B
  ll avail = (ll)ws_size - (ll)fixed - 4096;
  int BPC = (int)(avail / per_b);
  if (BPC < 1) BPC = 1; if (BPC > 16) BPC = 16;
  u16* y2c = (u16*)(wsb + fixed);
  u16* y3c = y2c + (size_t)BPC*565*10240;

  hipMemsetAsync(facc, 0, 20480*4, stream);
  k_probe<<<1,256,0,stream>>>((const u16*)w_fc1, flagp);
  // weight preps
  k_wprep<<<6,  256,0,stream>>>(w_c1, w1p, 3,  24,  1, flagp, 0);
  k_wprep<<<128,256,0,stream>>>(w_c2, w2p, 32, 256, 2, flagp, 1);   // kc-major
  k_wprep<<<512,256,0,stream>>>(w_c3, w3p, 64, 512, 4, flagp, 0);
  k_deg<<<565,64,0,stream>>>(graph, dinv, flagp);
  k_norm<<<1272,256,0,stream>>>(graph, dinv, normTp, flagp);
  k_bswz<<<68, 256,0,stream>>>(w_g1, bswg1, 64, 2176, 64, 68, 4, 1, 0, 0, flagp, 1);
  k_bswz<<<2,  256,0,stream>>>(w_g2, bswg2, 64, 64,   64, 2,  4, 1, 0, 0, flagp, 1);
  k_mvp<<<36,256,0,stream>>>(mv, mvp, flagp);
  // conv stack + GEMM1, chunked by batch (stream order makes reuse safe)
  for (int cb = 0; cb < 16; cb += BPC){
    int nb = 16 - cb; if (nb > BPC) nb = BPC;
    int rows = nb*565;
    k_conv12<<<rows,256,0,stream>>>(wav, w1p, w2p, b_c1, b_c2, y2c, cb*565, flagp);
    k_conv3<<<(rows+2)/3,256,0,stream>>>(y2c, cb*565, rows, cb, w3p, b_c3, y3c, flagp);
    k_gemm565<<<nb*9,256,0,stream>>>(y3c, 1229440LL, 2176, bswg1, 0LL, 68, nullptr, 0,
                                     hbuf + (size_t)cb*36160, 36160LL, flagp);
  }
  // GCN aggregations
  k_bswz<<<288,256,0,stream>>>(hbuf, bswh, 64, 565, 64, 18, 4, 16, 36160LL, 36864LL, flagp, 0);
  k_gemm565<<<144,256,0,stream>>>(normTp, 0LL, 576, bswh, 36864LL, 18, b_g1, 1, z1, 36160LL, flagp);
  k_gemm565<<<144,256,0,stream>>>(z1, 36160LL, 64, bswg2, 0LL, 2, nullptr, 0, h2, 36160LL, flagp);
  k_bswz<<<288,256,0,stream>>>(h2, bswh2, 64, 565, 64, 18, 4, 16, 36160LL, 36864LL, flagp, 0);
  k_gemm565<<<144,256,0,stream>>>(normTp, 0LL, 576, bswh2, 36864LL, 18, b_g2, 2, z2, 36160LL, flagp);
  // head assembly
  k_fc1<<<dim3(20,48),256,0,stream>>>(z2, w_fc1, facc, flagp);
  k_asm<<<116,256,0,stream>>>(facc, b_fc1, meta, zbuf, flagp);
  k_fce<<<36,64,0,stream>>>(mvp, w_fce, b_fce, zbuf, flagp);
  k_heads<<<180,64,0,stream>>>(zbuf, w_h0, w_h1, w_h2, w_h3, w_h4,
                               b_h0, b_h1, b_h2, b_h3, b_h4, d_out, flagp);
}

// Round 3
// 2061.987 us; speedup vs baseline: 1.2845x; 1.1339x over previous
//
#include <hip/hip_runtime.h>

using u16 = unsigned short;
using u32 = unsigned int;
using ll  = long long;

typedef __attribute__((ext_vector_type(8)))  short bf8_t;   // 8 bf16 (4 VGPRs)
typedef __attribute__((ext_vector_type(4)))  float f32x4;
typedef __attribute__((ext_vector_type(16))) float f32x16;

#define DEVI __device__ __forceinline__
#define MFMA32(a,b,c) __builtin_amdgcn_mfma_f32_32x32x16_bf16(a,b,c,0,0,0)

DEVI float b2f(u16 u){ union{u32 i; float f;} x; x.i=((u32)u)<<16; return x.f; }
DEVI u16 f2b(float f){ union{float f; u32 i;} x; x.f=f; u32 r=(x.i + 0x7fffu + ((x.i>>16)&1u))>>16; return (u16)r; }
DEVI f32x16 zero16(){ f32x16 v; for(int i=0;i<16;i++) v[i]=0.f; return v; }
// dtype-flexible input load: f==1 -> float32 buffer, f==0 -> bf16 buffer
DEVI float ldin(const void* p, ll i, int f){
  return f ? ((const float*)p)[i] : b2f(((const u16*)p)[i]);
}

DEVI bf8_t lds_frag(const u16* p){
  union{ u32 u[4]; bf8_t v; } t;
  const u32* q = (const u32*)p;
  t.u[0]=q[0]; t.u[1]=q[1]; t.u[2]=q[2]; t.u[3]=q[3];
  return t.v;
}
DEVI bf8_t g_frag(const u16* p){ return *(const bf8_t*)p; }

// ---------------- dtype probe: f32 mantissa junk has huge-exponent bf16 patterns ----------------
__global__ void k_probe(const u16* __restrict__ w, int* __restrict__ flag){
  __shared__ int cnt;
  if (threadIdx.x==0) cnt = 0;
  __syncthreads();
  int c = 0;
  for (int i = threadIdx.x; i < 65536; i += 256){
    u32 e = ((u32)w[i] >> 7) & 0xFF;
    if (e >= 0xC0) c++;
  }
  atomicAdd(&cnt, c);
  __syncthreads();
  if (threadIdx.x==0) *flag = (cnt > 64) ? 1 : 0;
}

// ---------------- conv weights -> 32x32x16 A-frag order ----------------
// kcMajor=0: [mt][kc][64lane*8]  (conv1, conv3)
// kcMajor=1: [kc][mt][64lane*8]  (conv2: a0/a1 adjacent per kc -> L1-friendly)
__global__ void k_wprep(const void* __restrict__ w, u16* __restrict__ dst, int C, int CH, int MT,
                        const int* __restrict__ flagp, int kcMajor){
  int tid = blockIdx.x*256 + threadIdx.x;
  int total = MT*CH*64;
  if (tid >= total) return;
  int f = *flagp;
  int l = tid & 63;
  int rest = tid >> 6;
  int kc = rest % CH;
  int mt = rest / CH;
  int o  = mt*32 + (l & 31);
  int c  = kc >> 3;
  int tap0 = (kc & 7)*16 + ((l>>5)&1)*8;
  union{ u16 v[8]; bf8_t vv; } t;
  for (int j=0;j<8;j++){
    int tap = tap0 + j;
    t.v[j] = (tap < 125) ? f2b(ldin(w, (ll)(o*C + c)*125 + tap, f)) : (u16)0;
  }
  size_t didx = kcMajor ? ((size_t)(kc*MT + mt)*64 + l) : (size_t)tid;
  *(bf8_t*)(dst + didx*8) = t.vv;
}

// ---------------- graph norm ----------------
__global__ void k_deg(const void* __restrict__ A, float* __restrict__ dinv,
                      const int* __restrict__ flagp){
  int c = blockIdx.x; int l = threadIdx.x; int f = *flagp;
  float s = 0.f;
  for (int r = l; r < 565; r += 64) s += ldin(A, (ll)c*565 + r, f);
  for (int off=32; off; off>>=1) s += __shfl_down(s, off, 64);
  if (l==0) dinv[c] = 1.0f / sqrtf(s + 1.0f);
}

__global__ void k_norm(const void* __restrict__ A, const float* __restrict__ dinv,
                       u16* __restrict__ normTp, const int* __restrict__ flagp){
  int i = blockIdx.x*256 + threadIdx.x;
  if (i >= 565*576) return;
  int f = *flagp;
  int c = i / 576, r = i - c*576;
  float v = 0.f;
  if (r < 565){
    float a = ldin(A, (ll)r*565 + c, f);
    if (r == c) a += 1.0f;
    v = dinv[c]*dinv[r]*a;
  }
  normTp[c*576 + r] = f2b(v);
}

// ---------------- generic B -> 16x16x32 frag swizzle ----------------
__global__ void k_bswz(const void* __restrict__ src, u16* __restrict__ dst,
                       int srcLd, int Kv, int Nv, int kcC, int ntC, int batch,
                       ll srcBS, ll dstBS, const int* __restrict__ flagp, int useF){
  int tid = blockIdx.x*256 + threadIdx.x;
  int total = batch*ntC*kcC*64;
  if (tid >= total) return;
  int f = useF ? *flagp : 0;
  int l = tid & 63;
  int rest = tid >> 6;
  int kc = rest % kcC; rest /= kcC;
  int nt = rest % ntC; int bi = rest/ntC;
  int n  = nt*16 + (l&15);
  int k0 = kc*32 + ((l>>4)&3)*8;
  union{ u16 v[8]; bf8_t vv; } t;
  for (int j=0;j<8;j++){
    int k = k0 + j;
    t.v[j] = (k < Kv && n < Nv) ? f2b(ldin(src, (ll)bi*srcBS + (ll)k*srcLd + n, f)) : (u16)0;
  }
  *(bf8_t*)(dst + (size_t)bi*dstBS + ((size_t)(nt*kcC + kc)*64 + l)*8) = t.vv;
}

__global__ void k_mvp(const void* __restrict__ mv, u16* __restrict__ mvp,
                      const int* __restrict__ flagp){
  int i = blockIdx.x*256 + threadIdx.x; if (i >= 16*576) return;
  int f = *flagp;
  int b = i/576, k = i - b*576;
  mvp[i] = (k < 565) ? f2b(ldin(mv, (ll)b*565 + k, f)) : (u16)0;
}

// ---------------- fused conv1+conv2 ----------------
// conv2 wave roles: wave0/1 = och-grp w, pos-tiles {0,1,2}; wave2 = both och, tile3;
// wave3 = both och, tile4. a-frag loads are explicitly software-pipelined (4-kc
// chunks, ping-pong regs) so L1 latency hides under MFMA issue.
__launch_bounds__(256, 2)
__global__ void k_conv12(const void* __restrict__ wav, const u16* __restrict__ w1p,
                         const u16* __restrict__ w2p, const void* __restrict__ b1,
                         const void* __restrict__ b2, u16* __restrict__ y2c, int rowBase,
                         const int* __restrict__ flagp){
  __shared__ uint4 ldsr[2138];            // 34,208 B = wavT[3][1004] + y1T[32][440]
  u16* lds = (u16*)ldsr;
  const int Y1B = 3024;
  int tid = threadIdx.x; int row = rowBase + blockIdx.x;
  int f = *flagp;
  int l = tid&63, w = tid>>6;
  int lq = (l>>5)&1, col = l&31;
  for (int i = tid; i < 3012; i += 256){
    int c = i/1004; int t = i - c*1004;
    lds[i] = (t < 1000) ? f2b(ldin(wav, (ll)row*3000 + t*3 + c, f)) : (u16)0;
  }
  __syncthreads();
  // conv1: tiles w+4t; tiles 14,15 (w>=2, t==3) cover pos >=448 > 437 -> dead, skip
  int wq = (w >= 2);
  f32x16 acc[4];
  #pragma unroll
  for(int t=0;t<4;t++) acc[t] = zero16();
  int pm1[4], pr1[4];
  #pragma unroll
  for(int t=0;t<4;t++){ int p = (w + 4*t)*32 + col; pm1[t]=p; pr1[t] = p>437?437:p; }
  {
    const u16* w1b = w1p + (size_t)l*8;
    bf8_t W0[4], W1[4];
    #pragma unroll
    for(int kk=0;kk<4;kk++) W0[kk] = g_frag(w1b + (size_t)kk*512);
    for (int g=0; g<6; g+=2){
      #pragma unroll
      for(int kk=0;kk<4;kk++) W1[kk] = g_frag(w1b + (size_t)((g+1)*4+kk)*512);
      #pragma unroll
      for(int kk=0;kk<4;kk++){
        int kc = g*4+kk;
        int ab = (kc>>3)*1004 + ((kc&7)*16 + lq*8);
        #pragma unroll
        for(int t=0;t<4;t++){
          if (t==3 && wq) continue;
          acc[t] = MFMA32(W0[kk], lds_frag(lds + ab + 2*pr1[t]), acc[t]);
        }
      }
      if (g+2 < 6){
        #pragma unroll
        for(int kk=0;kk<4;kk++) W0[kk] = g_frag(w1b + (size_t)((g+2)*4+kk)*512);
      }
      #pragma unroll
      for(int kk=0;kk<4;kk++){
        int kc = (g+1)*4+kk;
        int ab = (kc>>3)*1004 + ((kc&7)*16 + lq*8);
        #pragma unroll
        for(int t=0;t<4;t++){
          if (t==3 && wq) continue;
          acc[t] = MFMA32(W1[kk], lds_frag(lds + ab + 2*pr1[t]), acc[t]);
        }
      }
    }
  }
  float bv1[16];
  #pragma unroll
  for(int r=0;r<16;r++){ int om = (r&3) + 8*(r>>2) + 4*lq; bv1[r] = ldin(b1, om, f); }
  #pragma unroll
  for(int t=0;t<4;t++){
    if (pm1[t] < 438){
      #pragma unroll
      for(int r=0;r<16;r++){
        int om = (r&3) + 8*(r>>2) + 4*lq;
        float v = acc[t][r] + bv1[r]; v = v>0.f?v:0.f;
        lds[Y1B + om*440 + pm1[t]] = f2b(v);
      }
    }
  }
  if (tid < 64) lds[Y1B + (tid>>1)*440 + 438 + (tid&1)] = 0;
  __syncthreads();

  // conv2
  u16* y2row = y2c + (size_t)blockIdx.x*10240;
  if (w < 2){
    // och-major: 1 a-frag, 3 b-frags, 3 MFMA per kc; positions 0..95 always valid
    int ochb = w*32;
    f32x16 c0 = zero16(), c1 = zero16(), c2 = zero16();
    int p0 = col, p1 = 32 + col, p2 = 64 + col;
    const u16* wA = w2p + (size_t)w*512 + (size_t)l*8;
    bf8_t A0[4], A1[4];
    #pragma unroll
    for(int kk=0;kk<4;kk++) A0[kk] = g_frag(wA + (size_t)kk*1024);
    for (int g=0; g<64; g+=2){
      #pragma unroll
      for(int kk=0;kk<4;kk++) A1[kk] = g_frag(wA + (size_t)((g+1)*4+kk)*1024);
      #pragma unroll
      for(int kk=0;kk<4;kk++){
        int kc = g*4 + kk;
        int ab = Y1B + (kc>>3)*440 + ((kc&7)*16 + lq*8);
        c0 = MFMA32(A0[kk], lds_frag(lds + ab + 2*p0), c0);
        c1 = MFMA32(A0[kk], lds_frag(lds + ab + 2*p1), c1);
        c2 = MFMA32(A0[kk], lds_frag(lds + ab + 2*p2), c2);
      }
      if (g+2 < 64){
        #pragma unroll
        for(int kk=0;kk<4;kk++) A0[kk] = g_frag(wA + (size_t)((g+2)*4+kk)*1024);
      }
      #pragma unroll
      for(int kk=0;kk<4;kk++){
        int kc = (g+1)*4 + kk;
        int ab = Y1B + (kc>>3)*440 + ((kc&7)*16 + lq*8);
        c0 = MFMA32(A1[kk], lds_frag(lds + ab + 2*p0), c0);
        c1 = MFMA32(A1[kk], lds_frag(lds + ab + 2*p1), c1);
        c2 = MFMA32(A1[kk], lds_frag(lds + ab + 2*p2), c2);
      }
    }
    #pragma unroll
    for(int r=0;r<16;r++){
      int om = (r&3) + 8*(r>>2) + 4*lq;
      float bv = ldin(b2, ochb+om, f);
      float v0 = c0[r] + bv; v0 = v0>0.f?v0:0.f;
      float v1 = c1[r] + bv; v1 = v1>0.f?v1:0.f;
      float v2 = c2[r] + bv; v2 = v2>0.f?v2:0.f;
      y2row[(ochb+om)*160 + p0] = f2b(v0);
      y2row[(ochb+om)*160 + p1] = f2b(v1);
      y2row[(ochb+om)*160 + p2] = f2b(v2);
    }
  } else {
    // pos-major: 2 a-frags, 1 b-frag, 2 MFMA per kc; wave2=tile3 (valid), wave3=tile4 (clamped)
    f32x16 c0 = zero16(), c1 = zero16();
    int pf = (w+1)*32 + col; int p = pf>156?156:pf;
    const u16* wA = w2p + (size_t)l*8;
    bf8_t A0[8], A1[8];
    #pragma unroll
    for(int kk=0;kk<4;kk++){
      size_t o = (size_t)kk*1024;
      A0[2*kk] = g_frag(wA + o); A0[2*kk+1] = g_frag(wA + o + 512);
    }
    for (int g=0; g<64; g+=2){
      #pragma unroll
      for(int kk=0;kk<4;kk++){
        size_t o = (size_t)((g+1)*4+kk)*1024;
        A1[2*kk] = g_frag(wA + o); A1[2*kk+1] = g_frag(wA + o + 512);
      }
      #pragma unroll
      for(int kk=0;kk<4;kk++){
        int kc = g*4 + kk;
        int ab = Y1B + (kc>>3)*440 + ((kc&7)*16 + lq*8);
        bf8_t bf = lds_frag(lds + ab + 2*p);
        c0 = MFMA32(A0[2*kk],   bf, c0);
        c1 = MFMA32(A0[2*kk+1], bf, c1);
      }
      if (g+2 < 64){
        #pragma unroll
        for(int kk=0;kk<4;kk++){
          size_t o = (size_t)((g+2)*4+kk)*1024;
          A0[2*kk] = g_frag(wA + o); A0[2*kk+1] = g_frag(wA + o + 512);
        }
      }
      #pragma unroll
      for(int kk=0;kk<4;kk++){
        int kc = (g+1)*4 + kk;
        int ab = Y1B + (kc>>3)*440 + ((kc&7)*16 + lq*8);
        bf8_t bf = lds_frag(lds + ab + 2*p);
        c0 = MFMA32(A1[2*kk],   bf, c0);
        c1 = MFMA32(A1[2*kk+1], bf, c1);
      }
    }
    if (pf < 157){
      #pragma unroll
      for(int r=0;r<16;r++){
        int om = (r&3) + 8*(r>>2) + 4*lq;
        float v0 = c0[r] + ldin(b2, om, f);    v0 = v0>0.f?v0:0.f;
        float v1 = c1[r] + ldin(b2, 32+om, f); v1 = v1>0.f?v1:0.f;
        y2row[om*160 + pf]      = f2b(v0);
        y2row[(32+om)*160 + pf] = f2b(v1);
      }
    }
  }
  if (tid < 192){ int o = tid/3; y2row[o*160 + 157 + (tid - o*3)] = 0; }
}

// ---------------- conv3 (3 rows/WG), och-major waves, pipelined a-frags ----------------
__launch_bounds__(256, 2)
__global__ void k_conv3(const u16* __restrict__ y2c, int rowBase, int R, int batchBase,
                        const u16* __restrict__ w3p, const void* __restrict__ b3,
                        u16* __restrict__ y3c, const int* __restrict__ flagp){
  __shared__ uint4 lds4[3840];
  u16* lds = (u16*)lds4;
  int tid = threadIdx.x, wg = blockIdx.x;
  int f = *flagp;
  {
    const uint4* src = (const uint4*)y2c;
    ll lim = (ll)R*1280;
    ll base4 = (ll)wg*3840;
    for (int i = tid; i < 3840; i += 256){
      ll gi = base4 + i;
      uint4 v;
      if (gi < lim) v = src[gi]; else { v.x=0;v.y=0;v.z=0;v.w=0; }
      lds4[i] = v;
    }
  }
  __syncthreads();
  int l = tid&63, w = tid>>6;
  int lq = (l>>5)&1, col = l&31;
  int mt = w;                          // och tile (32 och) owned by this wave
  int pf0 = col,      pf1 = 32 + col; // both position halves
  int pc0 = pf0>50?50:pf0, pc1 = pf1>50?50:pf1;
  int g0 = pc0/17, wp0 = pc0 - g0*17;
  int g1 = pc1/17, wp1 = pc1 - g1*17;
  int bb0 = g0*10240 + 2*wp0;
  int bb1 = g1*10240 + 2*wp1;
  f32x16 ac0 = zero16(), ac1 = zero16();
  const u16* w3a = w3p + (size_t)mt*262144 + (size_t)l*8;
  bf8_t A0[4], A1[4];
  #pragma unroll
  for(int kk=0;kk<4;kk++) A0[kk] = g_frag(w3a + (size_t)kk*512);
  for (int g=0; g<128; g+=2){
    #pragma unroll
    for(int kk=0;kk<4;kk++) A1[kk] = g_frag(w3a + (size_t)((g+1)*4+kk)*512);
    #pragma unroll
    for(int kk=0;kk<4;kk++){
      int kc = g*4 + kk;
      int ab = (kc>>3)*160 + ((kc&7)*16 + lq*8);
      ac0 = MFMA32(A0[kk], lds_frag(lds + bb0 + ab), ac0);
      ac1 = MFMA32(A0[kk], lds_frag(lds + bb1 + ab), ac1);
    }
    if (g+2 < 128){
      #pragma unroll
      for(int kk=0;kk<4;kk++) A0[kk] = g_frag(w3a + (size_t)((g+2)*4+kk)*512);
    }
    #pragma unroll
    for(int kk=0;kk<4;kk++){
      int kc = (g+1)*4 + kk;
      int ab = (kc>>3)*160 + ((kc&7)*16 + lq*8);
      ac0 = MFMA32(A1[kk], lds_frag(lds + bb0 + ab), ac0);
      ac1 = MFMA32(A1[kk], lds_frag(lds + bb1 + ab), ac1);
    }
  }
  #pragma unroll
  for (int h=0; h<2; ++h){
    int pf = h ? pf1 : pf0;
    int g  = h ? g1  : g0;
    int wp = h ? wp1 : wp0;
    if (pf < 51 && (wg*3 + g) < R){
      int rowIdx = rowBase + wg*3 + g;
      int b = rowIdx/565; int n = rowIdx - b*565;
      int bb = b - batchBase;
      size_t obase = (size_t)bb*1229440 + (size_t)n*17 + wp;
      #pragma unroll
      for(int r=0;r<16;r++){
        int om = (r&3) + 8*(r>>2) + 4*lq;
        int o = mt*32 + om;
        float v = (h ? ac1[r] : ac0[r]) + ldin(b3, o, f); v = v>0.f?v:0.f;
        y3c[obase + (size_t)o*9605] = f2b(v);
      }
    }
  }
}

// ---------------- generic M=565-per-batch GEMM (16x16x32), N=64 ----------------
__global__ void k_gemm565(const u16* __restrict__ A, ll Abs, int lda,
                          const u16* __restrict__ bsw, ll Bbs, int KC,
                          const void* __restrict__ bias, int epi,
                          u16* __restrict__ outp, ll Obs, const int* __restrict__ flagp){
  int wg = blockIdx.x; int bi = wg/9; int mtg = wg - bi*9;
  int tid = threadIdx.x; int l = tid&63; int w = tid>>6;
  int f = *flagp;
  int Mt = mtg*4 + w;
  int m = Mt*16 + (l&15); int mc = m>564?564:m;
  int q = (l>>4)&3;
  const u16* Ab = A + (size_t)bi*Abs + (size_t)mc*lda + q*8;
  const u16* Bb = bsw + (size_t)bi*Bbs + (size_t)l*8;
  f32x4 ac[4];
  #pragma unroll
  for(int t=0;t<4;t++){ ac[t][0]=0;ac[t][1]=0;ac[t][2]=0;ac[t][3]=0; }
  for(int kc=0;kc<KC;kc++){
    bf8_t a = g_frag(Ab + kc*32);
    #pragma unroll
    for(int nt=0;nt<4;nt++){
      bf8_t bf = g_frag(Bb + (size_t)(nt*KC + kc)*512);
      ac[nt] = __builtin_amdgcn_mfma_f32_16x16x32_bf16(a, bf, ac[nt], 0,0,0);
    }
  }
  int rowb = q*4;
  #pragma unroll
  for(int nt=0;nt<4;nt++){
    int n = nt*16 + (l&15);
    float bv = bias ? ldin(bias, n, f) : 0.f;
    #pragma unroll
    for(int r=0;r<4;r++){
      int mm = Mt*16 + rowb + r;
      if (mm < 565){
        float v = ac[nt][r] + bv;
        if (epi==1) v = v>0.f?v:0.f;
        else if (epi==2) v = tanhf(v);
        outp[(size_t)bi*Obs + (size_t)mm*64 + n] = f2b(v);
      }
    }
  }
}

// ---------------- fc1: (16 x 36160) @ (36160 x 1280), K-split atomics ----------------
__global__ void k_fc1(const u16* __restrict__ z2, const void* __restrict__ wfc1,
                      float* __restrict__ acc, const int* __restrict__ flagp){
  int ng = blockIdx.x;     // 0..19
  int ks = blockIdx.y;     // 0..S-1
  int S  = gridDim.y;
  int tid = threadIdx.x; int l = tid&63; int w = tid>>6;
  int f = *flagp;
  int lo = (ks*1130)/S, hi = ((ks+1)*1130)/S;
  int colb = ng*64;
  int q = (l>>4)&3;
  f32x4 ac[4];
  #pragma unroll
  for(int t=0;t<4;t++){ ac[t][0]=0;ac[t][1]=0;ac[t][2]=0;ac[t][3]=0; }
  const u16* Ab = z2 + (size_t)(l&15)*36160 + q*8;
  for (int kc = lo + w; kc < hi; kc += 4){
    bf8_t a = g_frag(Ab + kc*32);
    int kb = kc*32 + q*8;
    #pragma unroll
    for (int nt=0;nt<4;nt++){
      int n = colb + nt*16 + (l&15);
      union{ u16 v[8]; bf8_t vv; } t;
      #pragma unroll
      for (int j=0;j<8;j++) t.v[j] = f2b(ldin(wfc1, (ll)(kb+j)*1280 + n, f));
      ac[nt] = __builtin_amdgcn_mfma_f32_16x16x32_bf16(a, t.vv, ac[nt], 0,0,0);
    }
  }
  int rowb = q*4;
  #pragma unroll
  for (int nt=0;nt<4;nt++){
    int n = colb + nt*16 + (l&15);
    #pragma unroll
    for (int r=0;r<4;r++) atomicAdd(&acc[(rowb+r)*1280 + n], ac[nt][r]);
  }
}

// ---------------- assemble z ----------------
__global__ void k_asm(const float* __restrict__ acc, const void* __restrict__ bfc1,
                      const void* __restrict__ meta, u16* __restrict__ z,
                      const int* __restrict__ flagp){
  int i = blockIdx.x*256 + threadIdx.x; if (i >= 16*1856) return;
  int f = *flagp;
  int b = i/1856, j = i - b*1856;
  if (j < 1280){ float v = acc[b*1280+j] + ldin(bfc1, j, f); z[i] = f2b(v>0.f?v:0.f); }
  else if (j < 1285) z[i] = f2b(ldin(meta, (ll)b*5 + (j-1280), f));
  else if (j >= 1850) z[i] = 0;
}

// ---------------- fc_extra into z cols [1285,1850), direct weight gather ----------------
__global__ void k_fce(const u16* __restrict__ mvp, const void* __restrict__ wfce,
                      const void* __restrict__ bias, u16* __restrict__ z,
                      const int* __restrict__ flagp){
  int nt = blockIdx.x; int l = threadIdx.x;
  int f = *flagp;
  int q = (l>>4)&3;
  f32x4 ac; ac[0]=0;ac[1]=0;ac[2]=0;ac[3]=0;
  const u16* Ab = mvp + (size_t)(l&15)*576 + q*8;
  int n = nt*16 + (l&15);
  for (int kc=0;kc<18;kc++){
    bf8_t a = g_frag(Ab + kc*32);
    union{ u16 v[8]; bf8_t vv; } t;
    #pragma unroll
    for (int j=0;j<8;j++){
      int k = kc*32 + q*8 + j;
      t.v[j] = (k < 565 && n < 565) ? f2b(ldin(wfce, (ll)k*565 + n, f)) : (u16)0;
    }
    ac = __builtin_amdgcn_mfma_f32_16x16x32_bf16(a, t.vv, ac, 0,0,0);
  }
  int rowb = q*4;
  if (n < 565){
    float bv = ldin(bias, n, f);
    #pragma unroll
    for (int r=0;r<4;r++){
      float v = ac[r] + bv; v = v>0.f?v:0.f;
      z[(size_t)(rowb+r)*1856 + 1285 + n] = f2b(v);
    }
  }
}

// ---------------- 5 output heads, direct weight gather, dtype-flexible store ----------------
__global__ void k_heads(const u16* __restrict__ z,
                        const void* __restrict__ wh0, const void* __restrict__ wh1,
                        const void* __restrict__ wh2, const void* __restrict__ wh3,
                        const void* __restrict__ wh4,
                        const void* __restrict__ bh0, const void* __restrict__ bh1,
                        const void* __restrict__ bh2, const void* __restrict__ bh3,
                        const void* __restrict__ bh4, void* __restrict__ out,
                        const int* __restrict__ flagp){
  int wg = blockIdx.x; int h = wg/36, nt = wg - h*36;
  int l = threadIdx.x;
  int f = *flagp;
  const void* wh   = (h==0)?wh0:(h==1)?wh1:(h==2)?wh2:(h==3)?wh3:wh4;
  const void* bias = (h==0)?bh0:(h==1)?bh1:(h==2)?bh2:(h==3)?bh3:bh4;
  int q = (l>>4)&3;
  f32x4 ac; ac[0]=0;ac[1]=0;ac[2]=0;ac[3]=0;
  const u16* Ab = z + (size_t)(l&15)*1856 + q*8;
  int n = nt*16 + (l&15);
  for (int kc=0;kc<58;kc++){
    bf8_t a = g_frag(Ab + kc*32);
    union{ u16 v[8]; bf8_t vv; } t;
    #pragma unroll
    for (int j=0;j<8;j++){
      int k = kc*32 + q*8 + j;
      t.v[j] = (k < 1850 && n < 565) ? f2b(ldin(wh, (ll)k*565 + n, f)) : (u16)0;
    }
    ac = __builtin_amdgcn_mfma_f32_16x16x32_bf16(a, t.vv, ac, 0,0,0);
  }
  int rowb = q*4;
  if (n < 565){
    float bv = ldin(bias, n, f);
    #pragma unroll
    for (int r=0;r<4;r++){
      float v = ac[r] + bv;
      size_t idx = (size_t)h*9040 + (size_t)(rowb+r)*565 + n;
      if (f) ((float*)out)[idx] = v; else ((u16*)out)[idx] = f2b(v);
    }
  }
}

extern "C" void kernel_launch(void* const* d_in, const int* in_sizes, int n_in,
                              void* d_out, int out_size, void* d_ws, size_t ws_size,
                              hipStream_t stream) {
  (void)in_sizes; (void)n_in; (void)out_size;
  const void* wav   = d_in[0];
  const void* graph = d_in[2];
  const void* meta  = d_in[3];
  const void* mv    = d_in[4];
  const void* w_c1  = d_in[5];  const void* b_c1 = d_in[6];
  const void* w_c2  = d_in[7];  const void* b_c2 = d_in[8];
  const void* w_c3  = d_in[9];  const void* b_c3 = d_in[10];
  const void* w_g1  = d_in[11]; const void* b_g1 = d_in[12];
  const void* w_g2  = d_in[13]; const void* b_g2 = d_in[14];
  const void* w_fce = d_in[15]; const void* b_fce= d_in[16];
  const void* w_fc1 = d_in[17]; const void* b_fc1= d_in[18];
  const void* w_h0 = d_in[19]; const void* b_h0 = d_in[20];
  const void* w_h1 = d_in[21]; const void* b_h1 = d_in[22];
  const void* w_h2 = d_in[23]; const void* b_h2 = d_in[24];
  const void* w_h3 = d_in[25]; const void* b_h3 = d_in[26];
  const void* w_h4 = d_in[27]; const void* b_h4 = d_in[28];

  char* wsb = (char*)d_ws;
  size_t off = 0;
  auto carve = [&](size_t bytes)->char*{ char* p = wsb + off; off = (off + bytes + 255) & ~(size_t)255; return p; };
  int*  flagp = (int*) carve(4);
  u16*  w1p   = (u16*) carve(12288ull*2);
  u16*  w2p   = (u16*) carve(262144ull*2);
  u16*  w3p   = (u16*) carve(1048576ull*2);
  float* dinv = (float*)carve(576*4);
  u16*  normTp= (u16*) carve(576ull*576*2);
  u16*  bswg1 = (u16*) carve(139264ull*2);
  u16*  bswg2 = (u16*) carve(4096ull*2);
  u16*  hbuf  = (u16*) carve(578560ull*2);
  u16*  bswh  = (u16*) carve(589824ull*2);
  u16*  z1    = (u16*) carve(578560ull*2);
  u16*  h2    = (u16*) carve(578560ull*2);
  u16*  bswh2 = (u16*) carve(589824ull*2);
  u16*  z2    = (u16*) carve(578560ull*2);
  float* facc = (float*)carve(20480*4);
  u16*  zbuf  = (u16*) carve(16ull*1856*2);
  u16*  mvp   = (u16*) carve(9216ull*2);
  // batch-chunked conv intermediates sized from the REAL ws_size
  size_t fixed = off;
  ll per_b = 565LL*10240*2 + 1229440LL*2;           // y2 + y3 per batch = 14,030,080 B
  ll avail = (ll)ws_size - (ll)fixed - 4096;
  int BPC = (int)(avail / per_b);
  if (BPC < 1) BPC = 1; if (BPC > 16) BPC = 16;
  u16* y2c = (u16*)(wsb + fixed);
  u16* y3c = y2c + (size_t)BPC*565*10240;

  hipMemsetAsync(facc, 0, 20480*4, stream);
  k_probe<<<1,256,0,stream>>>((const u16*)w_fc1, flagp);
  // weight preps
  k_wprep<<<6,  256,0,stream>>>(w_c1, w1p, 3,  24,  1, flagp, 0);
  k_wprep<<<128,256,0,stream>>>(w_c2, w2p, 32, 256, 2, flagp, 1);   // kc-major
  k_wprep<<<512,256,0,stream>>>(w_c3, w3p, 64, 512, 4, flagp, 0);
  k_deg<<<565,64,0,stream>>>(graph, dinv, flagp);
  k_norm<<<1272,256,0,stream>>>(graph, dinv, normTp, flagp);
  k_bswz<<<68, 256,0,stream>>>(w_g1, bswg1, 64, 2176, 64, 68, 4, 1, 0, 0, flagp, 1);
  k_bswz<<<2,  256,0,stream>>>(w_g2, bswg2, 64, 64,   64, 2,  4, 1, 0, 0, flagp, 1);
  k_mvp<<<36,256,0,stream>>>(mv, mvp, flagp);
  // conv stack + GEMM1, chunked by batch (stream order makes reuse safe)
  for (int cb = 0; cb < 16; cb += BPC){
    int nb = 16 - cb; if (nb > BPC) nb = BPC;
    int rows = nb*565;
    k_conv12<<<rows,256,0,stream>>>(wav, w1p, w2p, b_c1, b_c2, y2c, cb*565, flagp);
    k_conv3<<<(rows+2)/3,256,0,stream>>>(y2c, cb*565, rows, cb, w3p, b_c3, y3c, flagp);
    k_gemm565<<<nb*9,256,0,stream>>>(y3c, 1229440LL, 2176, bswg1, 0LL, 68, nullptr, 0,
                                     hbuf + (size_t)cb*36160, 36160LL, flagp);
  }
  // GCN aggregations
  k_bswz<<<288,256,0,stream>>>(hbuf, bswh, 64, 565, 64, 18, 4, 16, 36160LL, 36864LL, flagp, 0);
  k_gemm565<<<144,256,0,stream>>>(normTp, 0LL, 576, bswh, 36864LL, 18, b_g1, 1, z1, 36160LL, flagp);
  k_gemm565<<<144,256,0,stream>>>(z1, 36160LL, 64, bswg2, 0LL, 2, nullptr, 0, h2, 36160LL, flagp);
  k_bswz<<<288,256,0,stream>>>(h2, bswh2, 64, 565, 64, 18, 4, 16, 36160LL, 36864LL, flagp, 0);
  k_gemm565<<<144,256,0,stream>>>(normTp, 0LL, 576, bswh2, 36864LL, 18, b_g2, 2, z2, 36160LL, flagp);
  // head assembly
  k_fc1<<<dim3(20,48),256,0,stream>>>(z2, w_fc1, facc, flagp);
  k_asm<<<116,256,0,stream>>>(facc, b_fc1, meta, zbuf, flagp);
  k_fce<<<36,64,0,stream>>>(mvp, w_fce, b_fce, zbuf, flagp);
  k_heads<<<180,64,0,stream>>>(zbuf, w_h0, w_h1, w_h2, w_h3, w_h4,
                               b_h0, b_h1, b_h2, b_h3, b_h4, d_out, flagp);
}